// Round 17
// baseline (305.777 us; speedup 1.0000x reference)
//
#include <hip/hip_runtime.h>
#include <hip/hip_bf16.h>

// Problem constants: x (B,N,D) fp32; per-head SwiGLU FFN H=512.
#define B_ 8192
#define N_ 16
#define D_ 256
#define H_ 512

using bf16x8 = __attribute__((ext_vector_type(8))) short;
using f32x4  = __attribute__((ext_vector_type(4))) float;

__device__ __forceinline__ void gload_lds16(const void* g, void* l) {
    __builtin_amdgcn_global_load_lds(
        (const __attribute__((address_space(1))) void*)g,
        (__attribute__((address_space(3))) void*)l, 16, 0, 0);
}

__device__ __forceinline__ short f2bf(float f) {
    unsigned int u = __float_as_uint(f);
    u += 0x7fffu + ((u >> 16) & 1u);   // round-to-nearest-even
    return (short)(u >> 16);
}

__device__ __forceinline__ float bf2f(short s) {
    return __uint_as_float(((unsigned int)(unsigned short)s) << 16);
}

__device__ __forceinline__ unsigned int pack2(float lo, float hi) {
    return (unsigned int)(unsigned short)f2bf(lo)
         | ((unsigned int)(unsigned short)f2bf(hi) << 16);
}

__device__ __forceinline__ f32x4 mfma(bf16x8 a, bf16x8 b, f32x4 c) {
    return __builtin_amdgcn_mfma_f32_16x16x32_bf16(a, b, c, 0, 0, 0);
}

// Swizzled fragment read for [rows][64 cols] panels (8 granule slots):
// global granule g of row r lives in slot (g ^ r) & 7.  A wave's 64 lanes
// spread across all 8 16B-slots -> conflict-free ds_read_b128 (R10/R11: 0).
__device__ __forceinline__ bf16x8 rd64(const short* base, int row, int g) {
    int gp = (g ^ row) & 7;
    return *(const bf16x8*)&base[(row << 6) + (gp << 3)];
}

// ---------------------------------------------------------------------------
// Wide-M 2-sync GEMM core (R17): 256(M) x 128(N) tile, BK=64, NT K-tiles,
// 8 waves (4M x 2N), per-wave 64x64, acc[4][4] (64 regs, no cliff).
// Single-buffered 48 KiB LDS, 2 __syncthreads per K-step (R8/R10-verified
// semantics). 3 blocks/CU x 8 waves = 24 waves/CU co-residency.
// Staged bytes/MFMA -25% vs 128x128 (6 gloads/thread vs 8). FULLY UNROLLED
// K-loop with compile-time strides (R11: VALU off critical path).
// Staging: linear LDS dest + inverse-XOR global source (both-sides swizzle).
// ---------------------------------------------------------------------------
template<int NT, int SA, int SB>
__device__ __forceinline__ void gemmc(const short* __restrict__ Ag,
                                      const short* __restrict__ Bg,
                                      short* As, short* Bs,
                                      f32x4 (&acc)[4][4],
                                      int t, int rowA0, int rowB0) {
    int lane = t & 63;
    int l16 = lane & 15, kq = lane >> 4;
    // per-thread invariant staging geometry (512 thr: 64 rows per round)
    int srow = t >> 3;                 // 0..63 within a 64-row round
    int sg   = ((t & 7) ^ srow) & 7;   // inverse-XOR source granule
    const short* Asrc = Ag + (size_t)srow * SA + sg * 8;
    const short* Bsrc = Bg + (size_t)srow * SB + sg * 8;

#pragma unroll
    for (int kt = 0; kt < NT; ++kt) {
        const int k0 = kt * 64;
#pragma unroll
        for (int rnd = 0; rnd < 4; ++rnd)   // A: 256 rows
            gload_lds16(Asrc + rnd * 64 * SA + k0, As + rnd * 4096 + t * 8);
#pragma unroll
        for (int rnd = 0; rnd < 2; ++rnd)   // B: 128 rows
            gload_lds16(Bsrc + rnd * 64 * SB + k0, Bs + rnd * 4096 + t * 8);
        __syncthreads();   // drains vmcnt -> staged tile valid

#pragma unroll
        for (int kh = 0; kh < 2; ++kh) {
            int g = kh * 4 + kq;
            bf16x8 aF[4], bF[4];
#pragma unroll
            for (int j = 0; j < 4; ++j)
                bF[j] = rd64(Bs, rowB0 + j * 16 + l16, g);
#pragma unroll
            for (int i = 0; i < 4; ++i)
                aF[i] = rd64(As, rowA0 + i * 16 + l16, g);
#pragma unroll
            for (int i = 0; i < 4; ++i)
#pragma unroll
                for (int j = 0; j < 4; ++j)
                    acc[i][j] = mfma(aF[i], bF[j], acc[i][j]);
        }
        __syncthreads();   // protect WAR before next stage
    }
}

// ---------------------------------------------------------------------------
// k_prep: fp32 weights -> bf16.
//   wgu: [n][1024 rows][256] where row ri = (h>>4)*32 + which*16 + (h&15),
//        which 0=W1(gate), 1=W3(up)  -> G/U rows adjacent at 16-granularity.
//   w2t: [n][d][h]  (B^T of (H,D))
// ---------------------------------------------------------------------------
__global__ __launch_bounds__(256) void k_prep(const float* __restrict__ w1,
                                              const float* __restrict__ w3,
                                              const float* __restrict__ w2,
                                              short* __restrict__ wgu,
                                              short* __restrict__ w2t) {
    int o = blockIdx.x * 256 + threadIdx.x;      // 0 .. N*D*H-1 (2M)
    int n = o >> 17;                              // / (D*H = 131072)
    int r = o & 131071;
    int h = r >> 8, d = r & 255;
    size_t base = ((size_t)n * 1024 + (h >> 4) * 32 + (h & 15)) * 256 + d;
    wgu[base]            = f2bf(w1[(size_t)n * 131072 + (size_t)d * 512 + h]);
    wgu[base + 16 * 256] = f2bf(w3[(size_t)n * 131072 + (size_t)d * 512 + h]);
    int d2 = r >> 9, h2 = r & 511;                // [n][d][h] out layout
    w2t[o] = f2bf(w2[(size_t)n * 131072 + (size_t)h2 * 256 + d2]);
}

// ---------------------------------------------------------------------------
// k_mix (R10 version — measured best): rmsnorm1 -> head_mixing -> +x ->
// rmsnorm2. Wave-parallel float4 row sums + packed bf16x2 stores.
// Head-major outputs pb/pn [head][b][d].
// ---------------------------------------------------------------------------
__global__ __launch_bounds__(256) void k_mix(const float* __restrict__ x,
                                             const float* __restrict__ n1w,
                                             const float* __restrict__ n2w,
                                             unsigned int* __restrict__ pb_u,
                                             unsigned int* __restrict__ pn_u) {
    __shared__ __align__(16) float xs[N_ * D_];
    __shared__ __align__(16) float ps[N_ * D_];
    __shared__ float inv1[N_];
    __shared__ float inv2[N_];
    int b = blockIdx.x;
    int t = threadIdx.x;
    int w = t >> 6, lane = t & 63;

    const float4* xb4 = (const float4*)(x + (size_t)b * (N_ * D_));
    float4* xs4 = (float4*)xs;
    float4* ps4 = (float4*)ps;
#pragma unroll
    for (int i = 0; i < 4; ++i) xs4[t + i * 256] = xb4[t + i * 256];
    __syncthreads();

    // pass 1: row sums of x^2, one row per (wave, q), all 64 lanes active
#pragma unroll
    for (int q = 0; q < 4; ++q) {
        int row = w * 4 + q;
        float4 v = xs4[row * 64 + lane];
        float s = v.x * v.x + v.y * v.y + v.z * v.z + v.w * v.w;
        s += __shfl_xor(s, 1);  s += __shfl_xor(s, 2);
        s += __shfl_xor(s, 4);  s += __shfl_xor(s, 8);
        s += __shfl_xor(s, 16); s += __shfl_xor(s, 32);
        if (lane == 0) inv1[row] = rsqrtf(s * (1.0f / 256.0f) + 1e-6f);
    }
    __syncthreads();

    // head-mix + residual: thread owns column d = t
    {
        int n = t >> 4, j = t & 15;
        float i1 = inv1[n];
#pragma unroll 1
        for (int m = 0; m < 16; ++m) {
            float v = xs[n * 256 + m * 16 + j] * i1 * n1w[m * 16 + j]
                    + xs[m * 256 + t];
            ps[m * 256 + t] = v;
        }
    }
    __syncthreads();

    // pass 2: row sums of p^2
#pragma unroll
    for (int q = 0; q < 4; ++q) {
        int row = w * 4 + q;
        float4 v = ps4[row * 64 + lane];
        float s = v.x * v.x + v.y * v.y + v.z * v.z + v.w * v.w;
        s += __shfl_xor(s, 1);  s += __shfl_xor(s, 2);
        s += __shfl_xor(s, 4);  s += __shfl_xor(s, 8);
        s += __shfl_xor(s, 16); s += __shfl_xor(s, 32);
        if (lane == 0) inv2[row] = rsqrtf(s * (1.0f / 256.0f) + 1e-6f);
    }
    __syncthreads();

    // packed store: thread handles d-pair (2*dh, 2*dh+1) for 8 rows
    int dh = t & 127, mh = t >> 7;
    float wA = n2w[2 * dh], wB = n2w[2 * dh + 1];
#pragma unroll
    for (int i = 0; i < 8; ++i) {
        int m = mh * 8 + i;
        float2 f = *(const float2*)&ps[m * 256 + 2 * dh];
        float iv = inv2[m];
        size_t off = ((size_t)m * B_ + b) * (D_ / 2) + dh;
        pb_u[off] = pack2(f.x, f.y);
        pn_u[off] = pack2(f.x * iv * wA, f.y * iv * wB);
    }
}

// ---------------------------------------------------------------------------
// k_gu: [G|U] = Pn @ Wgu^T per head (M=8192/head, N=1024 interleaved, K=256),
// silu(G)*U epilogue -> hact [head][m][h] bf16.
// Tile 256(M) x 128(wgu rows), 512 thr, NT=4.
// ---------------------------------------------------------------------------
__global__ __launch_bounds__(512, 4) void k_gu(const short* __restrict__ pn,
                                               const short* __restrict__ wgu,
                                               short* __restrict__ hact) {
    __shared__ __align__(16) short As[256 * 64];   // 32 KiB
    __shared__ __align__(16) short Bs[128 * 64];   // 16 KiB

    // XCD-aware bijective swizzle: 4096 blocks, 512 per XCD chunk.
    int bid = blockIdx.x;
    int bx = (bid & 7) * 512 + (bid >> 3);
    int head = bx >> 8;           // 256 blocks/head
    int mt = (bx >> 3) & 31;      // nt fastest -> A-tile L2 reuse
    int nt = bx & 7;

    int t = threadIdx.x;
    int w = t >> 6, lane = t & 63;
    int l16 = lane & 15, kq = lane >> 4;
    int wm = w >> 1, wn = w & 1;  // 4M x 2N

    f32x4 acc[4][4];
#pragma unroll
    for (int i = 0; i < 4; ++i)
#pragma unroll
        for (int j = 0; j < 4; ++j) acc[i][j] = (f32x4){0.f, 0.f, 0.f, 0.f};

    const short* Ag = pn  + ((size_t)head * B_ + (size_t)mt * 256) * D_;
    const short* Bg = wgu + ((size_t)head * 1024 + (size_t)nt * 128) * D_;

    gemmc<4, 256, 256>(Ag, Bg, As, Bs, acc, t, wm * 64, wn * 64);

    // epilogue: B-row pairs (nf=0,1) and (2,3) are (G,U) of the same 16 h's.
    size_t hb = (size_t)head * B_ * H_;
#pragma unroll
    for (int mf = 0; mf < 4; ++mf) {
        int m = mt * 256 + wm * 64 + mf * 16 + kq * 4;
#pragma unroll
        for (int p = 0; p < 2; ++p) {
            int h = nt * 64 + (wn * 2 + p) * 16 + l16;
#pragma unroll
            for (int r = 0; r < 4; ++r) {
                float g = acc[mf][2 * p][r];
                float u = acc[mf][2 * p + 1][r];
                float hv = g * (1.0f / (1.0f + __expf(-g))) * u;
                hact[hb + (size_t)(m + r) * H_ + h] = f2bf(hv);
            }
        }
    }
}

// ---------------------------------------------------------------------------
// k_dn: Q = Hact @ W2 per head (M=8192/head, N=256, K=512) + pb -> (B,N,D).
// Tile 256(M) x 128(D), 512 thr, NT=8.
// ---------------------------------------------------------------------------
__global__ __launch_bounds__(512, 4) void k_dn(const short* __restrict__ hact,
                                               const short* __restrict__ w2t,
                                               const short* __restrict__ pb,
                                               float* __restrict__ out) {
    __shared__ __align__(16) short As[256 * 64];   // 32 KiB
    __shared__ __align__(16) short Bs[128 * 64];   // 16 KiB

    // XCD-aware bijective swizzle: 1024 blocks, 128 per XCD chunk.
    int bid = blockIdx.x;
    int bx = (bid & 7) * 128 + (bid >> 3);
    int head = bx >> 6;           // 64 blocks/head
    int mt = (bx >> 1) & 31;      // nt fastest -> A-tile L2 reuse
    int nt = bx & 1;

    int t = threadIdx.x;
    int w = t >> 6, lane = t & 63;
    int l16 = lane & 15, kq = lane >> 4;
    int wm = w >> 1, wn = w & 1;  // 4M x 2N

    f32x4 acc[4][4];
#pragma unroll
    for (int i = 0; i < 4; ++i)
#pragma unroll
        for (int j = 0; j < 4; ++j) acc[i][j] = (f32x4){0.f, 0.f, 0.f, 0.f};

    const short* Ag = hact + ((size_t)head * B_ + (size_t)mt * 256) * H_;
    const short* Bg = w2t  + ((size_t)head * D_ + (size_t)nt * 128) * H_;

    gemmc<8, 512, 512>(Ag, Bg, As, Bs, acc, t, wm * 64, wn * 64);

#pragma unroll
    for (int mf = 0; mf < 4; ++mf) {
        int m = mt * 256 + wm * 64 + mf * 16 + kq * 4;
#pragma unroll
        for (int nf = 0; nf < 4; ++nf) {
            int d = nt * 128 + wn * 64 + nf * 16 + l16;
#pragma unroll
            for (int r = 0; r < 4; ++r) {
                float v = acc[mf][nf][r]
                        + bf2f(pb[((size_t)head * B_ + m + r) * D_ + d]);
                out[(size_t)(m + r) * (N_ * D_) + head * D_ + d] = v;
            }
        }
    }
}

// ---------------------------------------------------------------------------
extern "C" void kernel_launch(void* const* d_in, const int* in_sizes, int n_in,
                              void* d_out, int out_size, void* d_ws, size_t ws_size,
                              hipStream_t stream) {
    const float* x   = (const float*)d_in[0];
    const float* n1w = (const float*)d_in[1];
    const float* n2w = (const float*)d_in[2];
    const float* w1  = (const float*)d_in[3];
    const float* w3  = (const float*)d_in[4];
    const float* w2  = (const float*)d_in[5];
    float* out = (float*)d_out;

    char* ws = (char*)d_ws;
    // ws layout (total ~268 MiB):
    short* wgu  = (short*)(ws);                       //  8 MiB (interleaved G/U)
    short* w2t  = (short*)(ws + (8ull   << 20));      //  4 MiB
    short* pn   = (short*)(ws + (12ull  << 20));      // 64 MiB (bf16, head-major)
    short* pb   = (short*)(ws + (76ull  << 20));      // 64 MiB (bf16, head-major)
    short* hact = (short*)(ws + (140ull << 20));      // 128 MiB (bf16, head-major)

    k_prep<<<(N_ * D_ * H_) / 256, 256, 0, stream>>>(w1, w3, w2, wgu, w2t);
    k_mix<<<B_, 256, 0, stream>>>(x, n1w, n2w,
                                  (unsigned int*)pb, (unsigned int*)pn);
    k_gu<<<N_ * (B_ / 256) * (1024 / 128), 512, 0, stream>>>(pn, wgu, hact);
    k_dn<<<N_ * (B_ / 256) * (D_ / 128), 512, 0, stream>>>(hact, w2t, pb, out);
}

// Round 18
// 278.974 us; speedup vs baseline: 1.0961x; 1.0961x over previous
//
#include <hip/hip_runtime.h>
#include <hip/hip_bf16.h>

// Problem constants: x (B,N,D) fp32; per-head SwiGLU FFN H=512.
#define B_ 8192
#define N_ 16
#define D_ 256
#define H_ 512

using bf16x8 = __attribute__((ext_vector_type(8))) short;
using f32x4  = __attribute__((ext_vector_type(4))) float;

__device__ __forceinline__ void gload_lds16(const void* g, void* l) {
    __builtin_amdgcn_global_load_lds(
        (const __attribute__((address_space(1))) void*)g,
        (__attribute__((address_space(3))) void*)l, 16, 0, 0);
}

__device__ __forceinline__ short f2bf(float f) {
    unsigned int u = __float_as_uint(f);
    u += 0x7fffu + ((u >> 16) & 1u);   // round-to-nearest-even
    return (short)(u >> 16);
}

__device__ __forceinline__ float bf2f(short s) {
    return __uint_as_float(((unsigned int)(unsigned short)s) << 16);
}

__device__ __forceinline__ unsigned int pack2(float lo, float hi) {
    return (unsigned int)(unsigned short)f2bf(lo)
         | ((unsigned int)(unsigned short)f2bf(hi) << 16);
}

__device__ __forceinline__ f32x4 mfma(bf16x8 a, bf16x8 b, f32x4 c) {
    return __builtin_amdgcn_mfma_f32_16x16x32_bf16(a, b, c, 0, 0, 0);
}

// Swizzled fragment read for [128 rows][64 cols] panels (8 granule slots):
// global granule g of row r lives in slot (g ^ r) & 7.  A wave's 64 lanes
// spread across all 8 16B-slots -> conflict-free ds_read_b128 (R10/R11: 0).
__device__ __forceinline__ bf16x8 rd64(const short* base, int row, int g) {
    int gp = (g ^ row) & 7;
    return *(const bf16x8*)&base[(row << 6) + (gp << 3)];
}

// ---------------------------------------------------------------------------
// GEMM core (best-measured config, R16): 128x128 tile, BK=64, NT K-tiles,
// 4 waves (2M x 2N), per-wave 64x64, acc[4][4]. Single-buffered 32 KiB LDS,
// 2 __syncthreads per K-step. 4 blocks/CU co-residency hides the barrier
// drain (m114). FULLY UNROLLED K-loop with compile-time strides.
// Staging: linear LDS dest + inverse-XOR global source (both-sides swizzle).
// R15/R17 lesson: larger tiles (wide-N / wide-M) lose L2/L3 locality
// (FETCH 37->99/58 MB) and regress — this geometry is the family optimum.
// ---------------------------------------------------------------------------
template<int NT, int SA, int SB>
__device__ __forceinline__ void gemmc(const short* __restrict__ Ag,
                                      const short* __restrict__ Bg,
                                      short* As, short* Bs,
                                      f32x4 (&acc)[4][4],
                                      int t, int rowA0, int rowB0) {
    int lane = t & 63;
    int l16 = lane & 15, kq = lane >> 4;
    // per-thread invariant staging geometry
    int srow = t >> 3;                 // 0..31 within a 32-row round
    int sg   = ((t & 7) ^ srow) & 7;   // inverse-XOR source granule
    const short* Asrc = Ag + (size_t)srow * SA + sg * 8;
    const short* Bsrc = Bg + (size_t)srow * SB + sg * 8;

#pragma unroll
    for (int kt = 0; kt < NT; ++kt) {
        const int k0 = kt * 64;
#pragma unroll
        for (int rnd = 0; rnd < 4; ++rnd)
            gload_lds16(Asrc + rnd * 32 * SA + k0, As + rnd * 2048 + t * 8);
#pragma unroll
        for (int rnd = 0; rnd < 4; ++rnd)
            gload_lds16(Bsrc + rnd * 32 * SB + k0, Bs + rnd * 2048 + t * 8);
        __syncthreads();

#pragma unroll
        for (int kh = 0; kh < 2; ++kh) {
            int g = kh * 4 + kq;
            bf16x8 aF[4], bF[4];
#pragma unroll
            for (int j = 0; j < 4; ++j)
                bF[j] = rd64(Bs, rowB0 + j * 16 + l16, g);
#pragma unroll
            for (int i = 0; i < 4; ++i)
                aF[i] = rd64(As, rowA0 + i * 16 + l16, g);
#pragma unroll
            for (int i = 0; i < 4; ++i)
#pragma unroll
                for (int j = 0; j < 4; ++j)
                    acc[i][j] = mfma(aF[i], bF[j], acc[i][j]);
        }
        __syncthreads();
    }
}

// ---------------------------------------------------------------------------
// k_prep: fp32 weights -> bf16.
//   wgu: [n][1024 rows][256] where row ri = (h>>4)*32 + which*16 + (h&15),
//        which 0=W1(gate), 1=W3(up)  -> G/U rows adjacent at 16-granularity.
//   w2t: [n][d][h]  (B^T of (H,D))
// ---------------------------------------------------------------------------
__global__ __launch_bounds__(256) void k_prep(const float* __restrict__ w1,
                                              const float* __restrict__ w3,
                                              const float* __restrict__ w2,
                                              short* __restrict__ wgu,
                                              short* __restrict__ w2t) {
    int o = blockIdx.x * 256 + threadIdx.x;      // 0 .. N*D*H-1 (2M)
    int n = o >> 17;                              // / (D*H = 131072)
    int r = o & 131071;
    int h = r >> 8, d = r & 255;
    size_t base = ((size_t)n * 1024 + (h >> 4) * 32 + (h & 15)) * 256 + d;
    wgu[base]            = f2bf(w1[(size_t)n * 131072 + (size_t)d * 512 + h]);
    wgu[base + 16 * 256] = f2bf(w3[(size_t)n * 131072 + (size_t)d * 512 + h]);
    int d2 = r >> 9, h2 = r & 511;                // [n][d][h] out layout
    w2t[o] = f2bf(w2[(size_t)n * 131072 + (size_t)h2 * 256 + d2]);
}

// ---------------------------------------------------------------------------
// k_mix v3: rmsnorm1 -> head_mixing -> +x -> rmsnorm2.
// Wave-parallel float4 row sums; store phase re-mapped (R18): thread owns
// 4 consecutive d's x 4 rows -> contiguous float4 LDS re-read (conflict-free,
// same pattern as pass-2) + uint2 (8 B/lane) packed stores (G13 sweet spot).
// Head-major outputs pb/pn [head][b][d].
// ---------------------------------------------------------------------------
__global__ __launch_bounds__(256) void k_mix(const float* __restrict__ x,
                                             const float* __restrict__ n1w,
                                             const float* __restrict__ n2w,
                                             unsigned int* __restrict__ pb_u,
                                             unsigned int* __restrict__ pn_u) {
    __shared__ __align__(16) float xs[N_ * D_];
    __shared__ __align__(16) float ps[N_ * D_];
    __shared__ float inv1[N_];
    __shared__ float inv2[N_];
    int b = blockIdx.x;
    int t = threadIdx.x;
    int w = t >> 6, lane = t & 63;

    const float4* xb4 = (const float4*)(x + (size_t)b * (N_ * D_));
    float4* xs4 = (float4*)xs;
    float4* ps4 = (float4*)ps;
#pragma unroll
    for (int i = 0; i < 4; ++i) xs4[t + i * 256] = xb4[t + i * 256];
    __syncthreads();

    // pass 1: row sums of x^2, one row per (wave, q), all 64 lanes active
#pragma unroll
    for (int q = 0; q < 4; ++q) {
        int row = w * 4 + q;
        float4 v = xs4[row * 64 + lane];
        float s = v.x * v.x + v.y * v.y + v.z * v.z + v.w * v.w;
        s += __shfl_xor(s, 1);  s += __shfl_xor(s, 2);
        s += __shfl_xor(s, 4);  s += __shfl_xor(s, 8);
        s += __shfl_xor(s, 16); s += __shfl_xor(s, 32);
        if (lane == 0) inv1[row] = rsqrtf(s * (1.0f / 256.0f) + 1e-6f);
    }
    __syncthreads();

    // head-mix + residual: thread owns column d = t
    {
        int n = t >> 4, j = t & 15;
        float i1 = inv1[n];
#pragma unroll 1
        for (int m = 0; m < 16; ++m) {
            float v = xs[n * 256 + m * 16 + j] * i1 * n1w[m * 16 + j]
                    + xs[m * 256 + t];
            ps[m * 256 + t] = v;
        }
    }
    __syncthreads();

    // pass 2: row sums of p^2
#pragma unroll
    for (int q = 0; q < 4; ++q) {
        int row = w * 4 + q;
        float4 v = ps4[row * 64 + lane];
        float s = v.x * v.x + v.y * v.y + v.z * v.z + v.w * v.w;
        s += __shfl_xor(s, 1);  s += __shfl_xor(s, 2);
        s += __shfl_xor(s, 4);  s += __shfl_xor(s, 8);
        s += __shfl_xor(s, 16); s += __shfl_xor(s, 32);
        if (lane == 0) inv2[row] = rsqrtf(s * (1.0f / 256.0f) + 1e-6f);
    }
    __syncthreads();

    // store: thread t handles d-quad dq (4 d's) for 4 rows (wave = row group)
    int dq = t & 63;               // 64 quads cover d = 0..255
    int rg = t >> 6;               // 4 row groups of 4 rows
    float4 w4 = *(const float4*)&n2w[dq * 4];
#pragma unroll
    for (int i = 0; i < 4; ++i) {
        int m = rg * 4 + i;
        float4 f = *(const float4*)&ps[m * 256 + dq * 4];   // contig 1KB/wave
        float iv = inv2[m];
        size_t off = ((size_t)m * B_ + b) * 64 + dq;        // uint2 units
        ((uint2*)pb_u)[off] = make_uint2(pack2(f.x, f.y), pack2(f.z, f.w));
        ((uint2*)pn_u)[off] = make_uint2(pack2(f.x * iv * w4.x, f.y * iv * w4.y),
                                         pack2(f.z * iv * w4.z, f.w * iv * w4.w));
    }
}

// ---------------------------------------------------------------------------
// k_gu: [G|U] = Pn @ Wgu^T per head (M=8192/head, N=1024 interleaved, K=256),
// silu(G)*U epilogue -> hact [head][m][h] bf16. 128x128 tile, BK=64, NT=4.
// ---------------------------------------------------------------------------
__global__ __launch_bounds__(256, 4) void k_gu(const short* __restrict__ pn,
                                               const short* __restrict__ wgu,
                                               short* __restrict__ hact) {
    __shared__ __align__(16) short As[128 * 64];
    __shared__ __align__(16) short Bs[128 * 64];

    // XCD-aware bijective swizzle: 8192 blocks, 1024 per XCD chunk.
    int bid = blockIdx.x;
    int bx = (bid & 7) * 1024 + (bid >> 3);
    int head = bx >> 9;
    int mt = (bx >> 3) & 63;      // nt fastest -> A-tile L2 reuse
    int nt = bx & 7;

    int t = threadIdx.x;
    int w = t >> 6, lane = t & 63;
    int l16 = lane & 15, kq = lane >> 4;
    int wm = w >> 1, wn = w & 1;

    f32x4 acc[4][4];
#pragma unroll
    for (int i = 0; i < 4; ++i)
#pragma unroll
        for (int j = 0; j < 4; ++j) acc[i][j] = (f32x4){0.f, 0.f, 0.f, 0.f};

    const short* Ag = pn  + ((size_t)head * B_ + (size_t)mt * 128) * D_;
    const short* Bg = wgu + ((size_t)head * 1024 + (size_t)nt * 128) * D_;

    gemmc<4, 256, 256>(Ag, Bg, As, Bs, acc, t, wm * 64, wn * 64);

    // epilogue: B-row pairs (nf=0,1) and (2,3) are (G,U) of the same 16 h's.
    size_t hb = (size_t)head * B_ * H_;
#pragma unroll
    for (int mf = 0; mf < 4; ++mf) {
        int m = mt * 128 + wm * 64 + mf * 16 + kq * 4;
#pragma unroll
        for (int p = 0; p < 2; ++p) {
            int h = nt * 64 + (wn * 2 + p) * 16 + l16;
#pragma unroll
            for (int r = 0; r < 4; ++r) {
                float g = acc[mf][2 * p][r];
                float u = acc[mf][2 * p + 1][r];
                float hv = g * (1.0f / (1.0f + __expf(-g))) * u;
                hact[hb + (size_t)(m + r) * H_ + h] = f2bf(hv);
            }
        }
    }
}

// ---------------------------------------------------------------------------
// k_dn: Q = Hact @ W2 per head (M=8192/head, N=256, K=512) + pb -> (B,N,D).
// 128x128 tile, BK=64, NT=8.
// ---------------------------------------------------------------------------
__global__ __launch_bounds__(256, 4) void k_dn(const short* __restrict__ hact,
                                               const short* __restrict__ w2t,
                                               const short* __restrict__ pb,
                                               float* __restrict__ out) {
    __shared__ __align__(16) short As[128 * 64];
    __shared__ __align__(16) short Bs[128 * 64];

    // XCD-aware bijective swizzle: 2048 blocks, 256 per XCD chunk.
    int bid = blockIdx.x;
    int bx = (bid & 7) * 256 + (bid >> 3);
    int head = bx >> 7;
    int mt = (bx >> 1) & 63;      // nt fastest -> A-tile L2 reuse
    int nt = bx & 1;

    int t = threadIdx.x;
    int w = t >> 6, lane = t & 63;
    int l16 = lane & 15, kq = lane >> 4;
    int wm = w >> 1, wn = w & 1;

    f32x4 acc[4][4];
#pragma unroll
    for (int i = 0; i < 4; ++i)
#pragma unroll
        for (int j = 0; j < 4; ++j) acc[i][j] = (f32x4){0.f, 0.f, 0.f, 0.f};

    const short* Ag = hact + ((size_t)head * B_ + (size_t)mt * 128) * H_;
    const short* Bg = w2t  + ((size_t)head * D_ + (size_t)nt * 128) * H_;

    gemmc<8, 512, 512>(Ag, Bg, As, Bs, acc, t, wm * 64, wn * 64);

#pragma unroll
    for (int mf = 0; mf < 4; ++mf) {
        int m = mt * 128 + wm * 64 + mf * 16 + kq * 4;
#pragma unroll
        for (int nf = 0; nf < 4; ++nf) {
            int d = nt * 128 + wn * 64 + nf * 16 + l16;
#pragma unroll
            for (int r = 0; r < 4; ++r) {
                float v = acc[mf][nf][r]
                        + bf2f(pb[((size_t)head * B_ + m + r) * D_ + d]);
                out[(size_t)(m + r) * (N_ * D_) + head * D_ + d] = v;
            }
        }
    }
}

// ---------------------------------------------------------------------------
extern "C" void kernel_launch(void* const* d_in, const int* in_sizes, int n_in,
                              void* d_out, int out_size, void* d_ws, size_t ws_size,
                              hipStream_t stream) {
    const float* x   = (const float*)d_in[0];
    const float* n1w = (const float*)d_in[1];
    const float* n2w = (const float*)d_in[2];
    const float* w1  = (const float*)d_in[3];
    const float* w3  = (const float*)d_in[4];
    const float* w2  = (const float*)d_in[5];
    float* out = (float*)d_out;

    char* ws = (char*)d_ws;
    // ws layout (total ~268 MiB):
    short* wgu  = (short*)(ws);                       //  8 MiB (interleaved G/U)
    short* w2t  = (short*)(ws + (8ull   << 20));      //  4 MiB
    short* pn   = (short*)(ws + (12ull  << 20));      // 64 MiB (bf16, head-major)
    short* pb   = (short*)(ws + (76ull  << 20));      // 64 MiB (bf16, head-major)
    short* hact = (short*)(ws + (140ull << 20));      // 128 MiB (bf16, head-major)

    k_prep<<<(N_ * D_ * H_) / 256, 256, 0, stream>>>(w1, w3, w2, wgu, w2t);
    k_mix<<<B_, 256, 0, stream>>>(x, n1w, n2w,
                                  (unsigned int*)pb, (unsigned int*)pn);
    k_gu<<<N_ * (B_ / 128) * (1024 / 128), 256, 0, stream>>>(pn, wgu, hact);
    k_dn<<<N_ * (B_ / 128) * (D_ / 128), 256, 0, stream>>>(hact, w2t, pb, out);
}